// Round 8
// baseline (179.776 us; speedup 1.0000x reference)
//
#include <hip/hip_runtime.h>
#include <hip/hip_bf16.h>
#include <stdint.h>

// ---------------- problem constants ----------------
#define BATCH 16
#define CDIM  1024
#define FWID  32
#define HW    1024
#define NA    1024
#define NTOT  (BATCH*NA)    // 16384
#define NCHUNK 16           // 4 mi-tiles * 4 wc waves = 16 chunks of 64 cols
#define MARGIN 0.6f

typedef __bf16 bf16x8 __attribute__((ext_vector_type(8)));
typedef float  f32x4  __attribute__((ext_vector_type(4)));
typedef unsigned short us4 __attribute__((ext_vector_type(4)));
typedef unsigned short us8 __attribute__((ext_vector_type(8)));
typedef float  f4     __attribute__((ext_vector_type(4)));

template<int OFF>
__device__ __forceinline__ us4 tr_read(uint32_t addr){
  us4 r;
  asm volatile("ds_read_b64_tr_b16 %0, %1 offset:%2" : "=v"(r) : "v"(addr), "n"(OFF));
  return r;
}

__device__ __forceinline__ void gload16(const unsigned short* g, unsigned short* l){
  __builtin_amdgcn_global_load_lds((const __attribute__((address_space(1))) void*)g,
                                   (__attribute__((address_space(3))) void*)l, 16, 0, 0);
}

union FragU  { us4 h[2]; bf16x8 v; };
union FragU8 { us8 u;    bf16x8 v; };

__device__ __forceinline__ void ins3(float& a, float& b, float& c, float v){
  if (v < c){
    c = v;
    if (c < b){ float t=b; b=c; c=t;
      if (b < a){ t=a; a=b; b=t; }
    }
  }
}

#define MFMA __builtin_amdgcn_mfma_f32_16x16x32_bf16

// ---------------------------------------------------------------------------
// Pass 1: fp32 [c][hw] -> bf16 TRANSPOSED [hw][c] + per-hw norm partials.
// ---------------------------------------------------------------------------
__global__ __launch_bounds__(256)
void convert_transpose(const float* __restrict__ S, const float* __restrict__ R,
                       unsigned short* __restrict__ tS, unsigned short* __restrict__ tR,
                       float* __restrict__ pnorm){
  const int blk = blockIdx.x;
  const int e   = blk >> 11;
  const int b   = (blk >> 7) & 15;
  const int hwT = (blk >> 3) & 15;
  const int cT  = blk & 7;
  const float* src = (e ? R : S) + (size_t)b*CDIM*HW;
  unsigned short* dst = (e ? tR : tS) + (size_t)b*HW*CDIM;

  const int t   = threadIdx.x;
  const int cj  = t & 15;
  const int hwg = t >> 4;
  const int hw0 = hwT*64 + hwg*4;
  const int c0  = cT*128 + cj*8;

  f4 col[8];
  #pragma unroll
  for (int i = 0; i < 8; ++i)
    col[i] = *(const f4*)&src[(size_t)(c0 + i)*HW + hw0];

  float sq0=0.f, sq1=0.f, sq2=0.f, sq3=0.f;
  #pragma unroll
  for (int j = 0; j < 4; ++j){
    us8 pk;
    float sq = 0.f;
    #pragma unroll
    for (int i = 0; i < 8; ++i){
      __hip_bfloat16 h = __float2bfloat16(col[i][j]);
      pk[i] = __builtin_bit_cast(unsigned short, h);
      const float g = __bfloat162float(h);
      sq = fmaf(g, g, sq);
    }
    *(us8*)&dst[(size_t)(hw0 + j)*CDIM + c0] = pk;
    if (j==0) sq0=sq; else if (j==1) sq1=sq; else if (j==2) sq2=sq; else sq3=sq;
  }
  #pragma unroll
  for (int m = 1; m < 16; m <<= 1){
    sq0 += __shfl_xor(sq0, m);
    sq1 += __shfl_xor(sq1, m);
    sq2 += __shfl_xor(sq2, m);
    sq3 += __shfl_xor(sq3, m);
  }
  if (cj == 0){
    f4 o = {sq0, sq1, sq2, sq3};
    *(f4*)&pnorm[((size_t)(e*16 + b)*8 + cT)*HW + hw0] = o;
  }
}

__global__ __launch_bounds__(256)
void norm_reduce(const float* __restrict__ pnorm, float* __restrict__ snorm){
  const int eb = blockIdx.x;
  const int t  = threadIdx.x;
  #pragma unroll
  for (int r = 0; r < 4; ++r){
    const int hw = r*256 + t;
    float a = 0.f;
    #pragma unroll
    for (int ct = 0; ct < 8; ++ct)
      a += pnorm[((size_t)eb*8 + ct)*HW + hw];
    snorm[(size_t)eb*HW + hw] = sqrtf(a);
  }
}

// ---------------------------------------------------------------------------
// ABLATION PROBE: staging+sync skeleton only (real gather pattern, same
// vmcnt/barrier schedule, no ds_read/MFMA). Its duration is recovered from
// total_dur arithmetic (it won't make the top-5 table).
// ---------------------------------------------------------------------------
__global__ __launch_bounds__(512, 2)
void gemm_skel1(const unsigned short* __restrict__ tS,
                const unsigned short* __restrict__ tR,
                const int* __restrict__ anchor,
                float* __restrict__ wsink)
{
  __shared__ unsigned short stage[49152];
  __shared__ int p_lds[256];

  const int t = threadIdx.x;
  const uint32_t bid = blockIdx.x;
  const uint32_t L = (bid & 7u)*32u + (bid >> 3);
  const int b  = L >> 4;
  const int ni = (L >> 2) & 3;
  const int mi = L & 3;

  const unsigned short* SbT = tS + (size_t)b*HW*CDIM;
  const unsigned short* RbT = tR + (size_t)b*HW*CDIM;

  if (t < 256){
    const int* ap = anchor + (size_t)(b*NA + ni*256 + t)*3;
    p_lds[t] = ap[2]*FWID + ap[1];
  }
  __syncthreads();

  const int l = t & 63;
  const int w = t >> 6;
  const int gkc = (l&3) ^ ((l>>3)&3);
  const int r0  = w*32 + (l>>2);
  const int r1  = r0 + 16;
  const unsigned short* gA0 = SbT + (size_t)p_lds[r0]*CDIM + gkc*8;
  const unsigned short* gA1 = SbT + (size_t)p_lds[r1]*CDIM + gkc*8;
  const unsigned short* gB0 = RbT + (size_t)(mi*256 + r0)*CDIM + gkc*8;
  const unsigned short* gB1 = RbT + (size_t)(mi*256 + r1)*CDIM + gkc*8;
  unsigned short* lA = &stage[w*1024];
  unsigned short* lB = &stage[24576 + w*1024];

  auto stage_fn = [&](int bo, int kt){
    const int ko = kt*32;
    gload16(gA0 + ko, lA + bo);
    gload16(gA1 + ko, lA + bo + 512);
    gload16(gB0 + ko, lB + bo);
    gload16(gB1 + ko, lB + bo + 512);
  };

  stage_fn(0, 0);
  stage_fn(8192, 1);
  int oc = 0, on = 8192, on2 = 16384;
  for (int kt = 0; kt < 32; ++kt){
    if (kt < 31) asm volatile("s_waitcnt vmcnt(4)" ::: "memory");
    else         asm volatile("s_waitcnt vmcnt(0)" ::: "memory");
    asm volatile("s_waitcnt lgkmcnt(0)" ::: "memory");
    __builtin_amdgcn_s_barrier();
    if (kt < 30) stage_fn(on2, kt+2);
    const int tmp = oc; oc = on; on = on2; on2 = tmp;
  }
  __syncthreads();
  // keep everything observably live: one LDS readback per thread
  float s = (float)stage[t*16];
  asm volatile("" : "+v"(s));
  if (l == 0) wsink[bid*8 + w] = s;
}

// ---------------------------------------------------------------------------
// Pass 2: v4 GEMM + epilogue run TWICE (second pass on opaqued acc -> same
// values; measures epilogue cost as dur - 82us). Real outputs unchanged.
// ---------------------------------------------------------------------------
__global__ __launch_bounds__(512, 2)
void fused_gemm_epi2(const unsigned short* __restrict__ tS,
                     const unsigned short* __restrict__ tR,
                     const float* __restrict__ snorm,
                     const int*   __restrict__ anchor,
                     const int*   __restrict__ posidx,
                     float* __restrict__ wtop,   // [NTOT][NCHUNK][3]
                     float* __restrict__ wpos,   // [NTOT]
                     float* __restrict__ wtop2,  // scratch (may alias wtop)
                     float* __restrict__ wpos2)  // scratch (may alias wpos)
{
  __shared__ unsigned short stage[49152];
  __shared__ int   p_lds[256], q_lds[256];
  __shared__ float nAs[256], nBs[256];

  const int t = threadIdx.x;
  const uint32_t bid = blockIdx.x;
  const uint32_t L = (bid & 7u)*32u + (bid >> 3);   // XCD swizzle (256%8==0)
  const int b  = L >> 4;
  const int ni = (L >> 2) & 3;
  const int mi = L & 3;

  const unsigned short* SbT = tS + (size_t)b*HW*CDIM;
  const unsigned short* RbT = tR + (size_t)b*HW*CDIM;

  if (t < 256){
    const int n_g = ni*256 + t;
    const int* ap = anchor + (size_t)(b*NA + n_g)*3;
    const int* pp = posidx + (size_t)(b*NA + n_g)*3;
    const int pv = ap[2]*FWID + ap[1];
    p_lds[t] = pv;
    q_lds[t] = pp[2]*FWID + pp[1];
    nAs[t] = snorm[(size_t)b*HW + pv];
  } else {
    nBs[t-256] = snorm[(size_t)(BATCH + b)*HW + mi*256 + (t-256)];
  }
  __syncthreads();

  const int l  = t & 63;
  const int w  = t >> 6;
  const int wr = w >> 2, wc = w & 3;

  const int gkc = (l&3) ^ ((l>>3)&3);
  const int r0  = w*32 + (l>>2);
  const int r1  = r0 + 16;
  const unsigned short* gA0 = SbT + (size_t)p_lds[r0]*CDIM + gkc*8;
  const unsigned short* gA1 = SbT + (size_t)p_lds[r1]*CDIM + gkc*8;
  const unsigned short* gB0 = RbT + (size_t)(mi*256 + r0)*CDIM + gkc*8;
  const unsigned short* gB1 = RbT + (size_t)(mi*256 + r1)*CDIM + gkc*8;
  unsigned short* lA = &stage[w*1024];
  unsigned short* lB = &stage[24576 + w*1024];

  const int fbase = (l&15)*32 + (((l>>4) ^ ((l>>1)&3))*8);
  const int abase = wr*4096 + fbase;
  const int bbase = 24576 + wc*2048 + fbase;

  f32x4 acc[8][4];
  #pragma unroll
  for (int i=0;i<8;i++){
    #pragma unroll
    for (int j=0;j<4;j++){ f32x4 z = {0.f,0.f,0.f,0.f}; acc[i][j] = z; }
  }

  auto stage_fn = [&](int bo, int kt){
    const int ko = kt*32;
    gload16(gA0 + ko, lA + bo);
    gload16(gA1 + ko, lA + bo + 512);
    gload16(gB0 + ko, lB + bo);
    gload16(gB1 + ko, lB + bo + 512);
  };

  auto compute = [&](int bo){
    FragU8 Bf[4], Af[8];
    #pragma unroll
    for (int fb=0; fb<4; ++fb) Bf[fb].u = *(const us8*)&stage[bbase + bo + fb*512];
    #pragma unroll
    for (int fa=0; fa<8; ++fa) Af[fa].u = *(const us8*)&stage[abase + bo + fa*512];
    #pragma unroll
    for (int fa=0; fa<8; ++fa){
      #pragma unroll
      for (int fb=0; fb<4; ++fb)
        acc[fa][fb] = MFMA(Af[fa].v, Bf[fb].v, acc[fa][fb], 0,0,0);
    }
  };

  stage_fn(0, 0);
  stage_fn(8192, 1);
  int oc = 0, on = 8192, on2 = 16384;
  for (int kt = 0; kt < 32; ++kt){
    if (kt < 31) asm volatile("s_waitcnt vmcnt(4)" ::: "memory");
    else         asm volatile("s_waitcnt vmcnt(0)" ::: "memory");
    asm volatile("s_waitcnt lgkmcnt(0)" ::: "memory");
    __builtin_amdgcn_s_barrier();
    if (kt < 30) stage_fn(on2, kt+2);
    compute(oc);
    const int tmp = oc; oc = on; on = on2; on2 = tmp;
  }

  float rncol[4];
  #pragma unroll
  for (int fb=0; fb<4; ++fb) rncol[fb] = nBs[wc*64 + fb*16 + (l&15)];

  auto epilogue = [&](float* __restrict__ wt, float* __restrict__ wp){
    #pragma unroll
    for (int fa=0; fa<8; ++fa){
      #pragma unroll
      for (int r=0; r<4; ++r){
        const int row_l = wr*128 + fa*16 + (l>>4)*4 + r;
        const int n_g   = ni*256 + row_l;
        const float an  = nAs[row_l];
        const float v0 = acc[fa][0][r] / fmaxf(an*rncol[0], 1e-8f);
        const float v1 = acc[fa][1][r] / fmaxf(an*rncol[1], 1e-8f);
        const float v2 = acc[fa][2][r] / fmaxf(an*rncol[2], 1e-8f);
        const float v3 = acc[fa][3][r] / fmaxf(an*rncol[3], 1e-8f);

        const int q  = q_lds[row_l];
        const int ql = q - (mi*256 + wc*64);
        if (ql >= 0 && ql < 64 && (ql & 15) == (l & 15)){
          const int sel = ql >> 4;
          const float pv = sel==0 ? v0 : sel==1 ? v1 : sel==2 ? v2 : v3;
          wp[b*NA + n_g] = pv;
        }

        float x=1e30f, y=1e30f, z=1e30f;
        ins3(x,y,z,v0); ins3(x,y,z,v1); ins3(x,y,z,v2); ins3(x,y,z,v3);
        #pragma unroll
        for (int m=1; m<16; m<<=1){
          const float ox = __shfl_xor(x, m);
          const float oy = __shfl_xor(y, m);
          const float oz = __shfl_xor(z, m);
          ins3(x,y,z,ox); ins3(x,y,z,oy); ins3(x,y,z,oz);
        }
        if ((l & 15) == 0){
          float* dst = wt + ((size_t)(b*NA + n_g)*NCHUNK + (mi*4 + wc))*3;
          dst[0]=x; dst[1]=y; dst[2]=z;
        }
      }
    }
  };

  epilogue(wtop, wpos);    // real outputs

  // opaque the acc (value-preserving) so the second epilogue can't be CSE'd
  #pragma unroll
  for (int i=0;i<8;i++){
    #pragma unroll
    for (int j=0;j<4;j++){
      #pragma unroll
      for (int k2=0;k2<4;k2++){
        float tmp = acc[i][j][k2];
        asm volatile("" : "+v"(tmp));
        acc[i][j][k2] = tmp;
      }
    }
  }
  epilogue(wtop2, wpos2);  // duplicated epilogue (same values; scratch or alias)
}

// ---------------------------------------------------------------------------
// v1 (verified) fused kernel — fallback when workspace is too small.
// ---------------------------------------------------------------------------
__global__ __launch_bounds__(256)
void fused_gemm_top3_v1(const float* __restrict__ sketch,
                        const float* __restrict__ refk,
                        const int*   __restrict__ anchor,
                        const int*   __restrict__ posidx,
                        float* __restrict__ wtop,
                        float* __restrict__ wpos)
{
  __shared__ union {
    unsigned short stage[16384];
    struct { float nA[16][128]; float nB[16][128]; } nrm;
  } sh;
  __shared__ int   p_lds[128];
  __shared__ float nA2[128], nB2[128];

  const int t = threadIdx.x;
  const uint32_t bid = blockIdx.x;
  const uint32_t L = (bid & 7u)*128u + (bid >> 3);
  const int b  = L >> 6;
  const int ni = (L >> 3) & 7;
  const int mi = L & 7;

  const float* Sb = sketch + (size_t)b*CDIM*HW;
  const float* Rb = refk   + (size_t)b*CDIM*HW;

  if (t < 128){
    const int n_g = ni*128 + t;
    const int* ap = anchor + (size_t)(b*NA + n_g)*3;
    p_lds[t] = ap[2]*FWID + ap[1];
  }
  __syncthreads();
  const int p0 = p_lds[0];
  int okf = 1;
  if (t < 128) okf = (p_lds[t] == p0 + t);
  const int contig = __syncthreads_and(okf);

  const int colg = (t & 15)*8;
  const int rowg = t >> 4;
  const int mbase = mi*128;

  const int l  = t & 63;
  const int w  = t >> 6;
  const int wr = w >> 1, wc = w & 1;
  const uint32_t sh_base = (uint32_t)(uintptr_t)&sh.stage[0];
  const uint32_t laneA = ((uint32_t)(l>>4))*2048u + (uint32_t)wr*512u + (uint32_t)(l&15)*8u;
  const uint32_t laneB = ((uint32_t)(l>>4))*2048u + (uint32_t)wc*512u + (uint32_t)(l&15)*8u;
  const int off0 = ((rowg>>2)*8 + (colg>>4))*64 + (rowg&3)*16 + (colg&15);

  f32x4 acc[4][4];
  #pragma unroll
  for (int i=0;i<4;i++){
    #pragma unroll
    for (int j=0;j<4;j++){ f32x4 z = {0.f,0.f,0.f,0.f}; acc[i][j] = z; }
  }

  float sqA[8] = {0,0,0,0,0,0,0,0};
  float sqB[8] = {0,0,0,0,0,0,0,0};
  f4 ra[4], rb[4];

  auto load_tile = [&](int kt){
    const int c0 = kt*32 + rowg;
    const float* SA = Sb + (size_t)c0*HW;
    const float* RB = Rb + (size_t)c0*HW + mbase + colg;
    if (contig){
      const float* pA = SA + p0 + colg;
      ra[0] = *(const f4*)(pA);
      ra[1] = *(const f4*)(pA + 4);
      ra[2] = *(const f4*)(pA + 16*HW);
      ra[3] = *(const f4*)(pA + 16*HW + 4);
    } else {
      float* raf = (float*)ra;
      #pragma unroll
      for (int i=0;i<8;i++){
        const int pc = p_lds[colg + i];
        raf[i]   = SA[pc];
        raf[8+i] = SA[16*HW + pc];
      }
    }
    rb[0] = *(const f4*)(RB);
    rb[1] = *(const f4*)(RB + 4);
    rb[2] = *(const f4*)(RB + 16*HW);
    rb[3] = *(const f4*)(RB + 16*HW + 4);
  };

  auto cvt_store = [&](int buf){
    const float* raf = (const float*)ra;
    const float* rbf = (const float*)rb;
    us8 pk;
    #pragma unroll
    for (int i=0;i<8;i++){
      __hip_bfloat16 h = __float2bfloat16(raf[i]);
      pk[i] = __builtin_bit_cast(unsigned short, h);
      const float g = __bfloat162float(h);
      sqA[i] = fmaf(g, g, sqA[i]);
    }
    *(us8*)&sh.stage[buf*4096 + off0] = pk;
    #pragma unroll
    for (int i=0;i<8;i++){
      __hip_bfloat16 h = __float2bfloat16(raf[8+i]);
      pk[i] = __builtin_bit_cast(unsigned short, h);
      const float g = __bfloat162float(h);
      sqA[i] = fmaf(g, g, sqA[i]);
    }
    *(us8*)&sh.stage[buf*4096 + off0 + 2048] = pk;
    #pragma unroll
    for (int i=0;i<8;i++){
      __hip_bfloat16 h = __float2bfloat16(rbf[i]);
      pk[i] = __builtin_bit_cast(unsigned short, h);
      const float g = __bfloat162float(h);
      sqB[i] = fmaf(g, g, sqB[i]);
    }
    *(us8*)&sh.stage[8192 + buf*4096 + off0] = pk;
    #pragma unroll
    for (int i=0;i<8;i++){
      __hip_bfloat16 h = __float2bfloat16(rbf[8+i]);
      pk[i] = __builtin_bit_cast(unsigned short, h);
      const float g = __bfloat162float(h);
      sqB[i] = fmaf(g, g, sqB[i]);
    }
    *(us8*)&sh.stage[8192 + buf*4096 + off0 + 2048] = pk;
  };

  auto compute = [&](int buf){
    const uint32_t aaddr = sh_base + (uint32_t)buf*8192u + laneA;
    const uint32_t baddr = sh_base + 16384u + (uint32_t)buf*8192u + laneB;
    FragU A0,A1,A2,A3,B0,B1,B2,B3;
    A0.h[0]=tr_read<0>(aaddr);    A0.h[1]=tr_read<1024>(aaddr);
    A1.h[0]=tr_read<128>(aaddr);  A1.h[1]=tr_read<1152>(aaddr);
    A2.h[0]=tr_read<256>(aaddr);  A2.h[1]=tr_read<1280>(aaddr);
    A3.h[0]=tr_read<384>(aaddr);  A3.h[1]=tr_read<1408>(aaddr);
    B0.h[0]=tr_read<0>(baddr);    B0.h[1]=tr_read<1024>(baddr);
    B1.h[0]=tr_read<128>(baddr);  B1.h[1]=tr_read<1152>(baddr);
    B2.h[0]=tr_read<256>(baddr);  B2.h[1]=tr_read<1280>(baddr);
    B3.h[0]=tr_read<384>(baddr);  B3.h[1]=tr_read<1408>(baddr);
    asm volatile("s_waitcnt lgkmcnt(0)" ::: "memory");
    __builtin_amdgcn_sched_barrier(0);
    acc[0][0]=MFMA(A0.v,B0.v,acc[0][0],0,0,0);
    acc[0][1]=MFMA(A0.v,B1.v,acc[0][1],0,0,0);
    acc[0][2]=MFMA(A0.v,B2.v,acc[0][2],0,0,0);
    acc[0][3]=MFMA(A0.v,B3.v,acc[0][3],0,0,0);
    acc[1][0]=MFMA(A1.v,B0.v,acc[1][0],0,0,0);
    acc[1][1]=MFMA(A1.v,B1.v,acc[1][1],0,0,0);
    acc[1][2]=MFMA(A1.v,B2.v,acc[1][2],0,0,0);
    acc[1][3]=MFMA(A1.v,B3.v,acc[1][3],0,0,0);
    acc[2][0]=MFMA(A2.v,B0.v,acc[2][0],0,0,0);
    acc[2][1]=MFMA(A2.v,B1.v,acc[2][1],0,0,0);
    acc[2][2]=MFMA(A2.v,B2.v,acc[2][2],0,0,0);
    acc[2][3]=MFMA(A2.v,B3.v,acc[2][3],0,0,0);
    acc[3][0]=MFMA(A3.v,B0.v,acc[3][0],0,0,0);
    acc[3][1]=MFMA(A3.v,B1.v,acc[3][1],0,0,0);
    acc[3][2]=MFMA(A3.v,B2.v,acc[3][2],0,0,0);
    acc[3][3]=MFMA(A3.v,B3.v,acc[3][3],0,0,0);
  };

  load_tile(0);
  cvt_store(0);
  __syncthreads();
  int buf = 0;
  for (int kt = 0; kt < 32; ++kt){
    if (kt < 31) load_tile(kt+1);
    compute(buf);
    if (kt < 31) cvt_store(buf^1);
    __syncthreads();
    buf ^= 1;
  }

  #pragma unroll
  for (int i=0;i<8;i++) sh.nrm.nA[rowg][colg+i] = sqA[i];
  #pragma unroll
  for (int i=0;i<8;i++) sh.nrm.nB[rowg][colg+i] = sqB[i];
  __syncthreads();
  if (t < 128){
    float s = 0.f;
    #pragma unroll
    for (int r=0;r<16;r++) s += sh.nrm.nA[r][t];
    nA2[t] = s;
  } else {
    const int c2 = t - 128;
    float s = 0.f;
    #pragma unroll
    for (int r=0;r<16;r++) s += sh.nrm.nB[r][c2];
    nB2[c2] = s;
  }
  __syncthreads();

  float rncol[4];
  #pragma unroll
  for (int nf=0;nf<4;nf++) rncol[nf] = sqrtf(nB2[wc*64 + nf*16 + (l&15)]);

  #pragma unroll
  for (int mf=0; mf<4; ++mf){
    #pragma unroll
    for (int r=0; r<4; ++r){
      const int row_l = wr*64 + mf*16 + (l>>4)*4 + r;
      const int n_g   = ni*128 + row_l;
      const float an  = sqrtf(nA2[row_l]);
      const float v0 = acc[mf][0][r] / fmaxf(an*rncol[0], 1e-8f);
      const float v1 = acc[mf][1][r] / fmaxf(an*rncol[1], 1e-8f);
      const float v2 = acc[mf][2][r] / fmaxf(an*rncol[2], 1e-8f);
      const float v3 = acc[mf][3][r] / fmaxf(an*rncol[3], 1e-8f);

      const int* pp = posidx + (size_t)(b*NA + n_g)*3;
      const int q  = pp[2]*FWID + pp[1];
      const int ql = q - (mbase + wc*64);
      if (ql >= 0 && ql < 64 && (ql & 15) == (l & 15)){
        const int sel = ql >> 4;
        const float pv = sel==0 ? v0 : sel==1 ? v1 : sel==2 ? v2 : v3;
        wpos[b*NA + n_g] = pv;
      }

      float x=1e30f, y=1e30f, z=1e30f;
      ins3(x,y,z,v0); ins3(x,y,z,v1); ins3(x,y,z,v2); ins3(x,y,z,v3);
      #pragma unroll
      for (int m=1; m<16; m<<=1){
        const float ox = __shfl_xor(x, m);
        const float oy = __shfl_xor(y, m);
        const float oz = __shfl_xor(z, m);
        ins3(x,y,z,ox); ins3(x,y,z,oy); ins3(x,y,z,oz);
      }
      if ((l & 15) == 0){
        float* dst = wtop + ((size_t)(b*NA + n_g)*NCHUNK + (mi*2 + wc))*3;
        dst[0]=x; dst[1]=y; dst[2]=z;
      }
    }
  }
}

// ---------------------------------------------------------------------------
__global__ __launch_bounds__(256)
void merge_top3(const float* __restrict__ wtop, const float* __restrict__ wpos,
                float* __restrict__ partial){
  __shared__ float red[256];
  const int id = blockIdx.x*256 + threadIdx.x;
  const float* src = wtop + (size_t)id*(NCHUNK*3);
  float x=1e30f, y=1e30f, z=1e30f;
  #pragma unroll
  for (int i=0;i<NCHUNK*3;i++) ins3(x,y,z, src[i]);
  const float loss = fmaxf((x+y+z) - wpos[id] + MARGIN, 0.0f);
  red[threadIdx.x] = loss;
  __syncthreads();
  for (int s=128; s>0; s>>=1){
    if (threadIdx.x < s) red[threadIdx.x] += red[threadIdx.x+s];
    __syncthreads();
  }
  if (threadIdx.x == 0) partial[blockIdx.x] = red[0];
}

__global__ void final_sum(const float* __restrict__ partial, float* __restrict__ out){
  float v = partial[threadIdx.x];
  #pragma unroll
  for (int off=32; off>0; off>>=1) v += __shfl_down(v, off);
  if (threadIdx.x == 0) out[0] = v / (1e-6f + (float)NTOT);
}

// ---------------------------------------------------------------------------
extern "C" void kernel_launch(void* const* d_in, const int* in_sizes, int n_in,
                              void* d_out, int out_size, void* d_ws, size_t ws_size,
                              hipStream_t stream){
  const float* sketch = (const float*)d_in[0];
  const float* refk   = (const float*)d_in[1];
  const int*   anchor = (const int*)d_in[2];
  const int*   posidx = (const int*)d_in[3];
  float* out = (float*)d_out;

  float* wtop    = (float*)d_ws;                       // NTOT*NCHUNK*3 floats
  float* wpos    = wtop + (size_t)NTOT*NCHUNK*3;       // NTOT floats
  float* partial = wpos + NTOT;                        // 64 floats (+pad)
  unsigned short* tS = (unsigned short*)(partial + 256);
  unsigned short* tR = tS + (size_t)BATCH*HW*CDIM;
  float* pnorm = (float*)(tR + (size_t)BATCH*HW*CDIM); // 32*8*1024 floats
  float* snorm = pnorm + (size_t)32*8*1024;            // 32*1024 floats
  float* wtop2 = snorm + (size_t)32*1024;              // scratch copy region
  float* wpos2 = wtop2 + (size_t)NTOT*NCHUNK*3;
  float* wsink = wpos2 + NTOT;                         // 2048 floats
  const size_t need1 = (size_t)((char*)wtop2 - (char*)d_ws);
  const size_t need2 = (size_t)((char*)(wsink + 2048) - (char*)d_ws);

  if (ws_size >= need2){
    convert_transpose<<<dim3(4096), dim3(256), 0, stream>>>(sketch, refk, tS, tR, pnorm);
    norm_reduce<<<dim3(32), dim3(256), 0, stream>>>(pnorm, snorm);
    gemm_skel1<<<dim3(256), dim3(512), 0, stream>>>(tS, tR, anchor, wsink);
    fused_gemm_epi2<<<dim3(256), dim3(512), 0, stream>>>(tS, tR, snorm, anchor, posidx,
                                                         wtop, wpos, wtop2, wpos2);
  } else if (ws_size >= need1){
    convert_transpose<<<dim3(4096), dim3(256), 0, stream>>>(sketch, refk, tS, tR, pnorm);
    norm_reduce<<<dim3(32), dim3(256), 0, stream>>>(pnorm, snorm);
    // second epilogue aliases the real outputs (same values -> harmless)
    fused_gemm_epi2<<<dim3(256), dim3(512), 0, stream>>>(tS, tR, snorm, anchor, posidx,
                                                         wtop, wpos, wtop, wpos);
  } else {
    fused_gemm_top3_v1<<<dim3(1024), dim3(256), 0, stream>>>(sketch, refk, anchor, posidx, wtop, wpos);
  }
  merge_top3<<<dim3(64), dim3(256), 0, stream>>>(wtop, wpos, partial);
  final_sum<<<dim3(1), dim3(64), 0, stream>>>(partial, out);
}

// Round 9
// 104.389 us; speedup vs baseline: 1.7222x; 1.7222x over previous
//
#include <hip/hip_runtime.h>
#include <hip/hip_bf16.h>
#include <stdint.h>

// ---------------- problem constants ----------------
#define BATCH 16
#define CDIM  1024
#define FWID  32
#define HW    1024
#define NA    1024
#define NTOT  (BATCH*NA)    // 16384
#define NCHUNK 16           // 4 mi-tiles * 4 wc waves = 16 chunks of 64 cols
#define MARGIN 0.6f

typedef __bf16 bf16x8 __attribute__((ext_vector_type(8)));
typedef float  f32x4  __attribute__((ext_vector_type(4)));
typedef unsigned short us4 __attribute__((ext_vector_type(4)));
typedef unsigned short us8 __attribute__((ext_vector_type(8)));
typedef float  f4     __attribute__((ext_vector_type(4)));

template<int OFF>
__device__ __forceinline__ us4 tr_read(uint32_t addr){
  us4 r;
  asm volatile("ds_read_b64_tr_b16 %0, %1 offset:%2" : "=v"(r) : "v"(addr), "n"(OFF));
  return r;
}

__device__ __forceinline__ void gload16(const unsigned short* g, unsigned short* l){
  __builtin_amdgcn_global_load_lds((const __attribute__((address_space(1))) void*)g,
                                   (__attribute__((address_space(3))) void*)l, 16, 0, 0);
}

union FragU  { us4 h[2]; bf16x8 v; };
union FragU8 { us8 u;    bf16x8 v; };

__device__ __forceinline__ void ins3(float& a, float& b, float& c, float v){
  if (v < c){
    c = v;
    if (c < b){ float t=b; b=c; c=t;
      if (b < a){ t=a; a=b; b=t; }
    }
  }
}

#define MFMA __builtin_amdgcn_mfma_f32_16x16x32_bf16

// ---------------------------------------------------------------------------
// Pass 1: fp32 [c][hw] -> bf16 TRANSPOSED [hw][c] + per-hw norm partials.
// ---------------------------------------------------------------------------
__global__ __launch_bounds__(256)
void convert_transpose(const float* __restrict__ S, const float* __restrict__ R,
                       unsigned short* __restrict__ tS, unsigned short* __restrict__ tR,
                       float* __restrict__ pnorm){
  const int blk = blockIdx.x;
  const int e   = blk >> 11;
  const int b   = (blk >> 7) & 15;
  const int hwT = (blk >> 3) & 15;
  const int cT  = blk & 7;
  const float* src = (e ? R : S) + (size_t)b*CDIM*HW;
  unsigned short* dst = (e ? tR : tS) + (size_t)b*HW*CDIM;

  const int t   = threadIdx.x;
  const int cj  = t & 15;
  const int hwg = t >> 4;
  const int hw0 = hwT*64 + hwg*4;
  const int c0  = cT*128 + cj*8;

  f4 col[8];
  #pragma unroll
  for (int i = 0; i < 8; ++i)
    col[i] = *(const f4*)&src[(size_t)(c0 + i)*HW + hw0];

  float sq0=0.f, sq1=0.f, sq2=0.f, sq3=0.f;
  #pragma unroll
  for (int j = 0; j < 4; ++j){
    us8 pk;
    float sq = 0.f;
    #pragma unroll
    for (int i = 0; i < 8; ++i){
      __hip_bfloat16 h = __float2bfloat16(col[i][j]);
      pk[i] = __builtin_bit_cast(unsigned short, h);
      const float g = __bfloat162float(h);
      sq = fmaf(g, g, sq);
    }
    *(us8*)&dst[(size_t)(hw0 + j)*CDIM + c0] = pk;
    if (j==0) sq0=sq; else if (j==1) sq1=sq; else if (j==2) sq2=sq; else sq3=sq;
  }
  #pragma unroll
  for (int m = 1; m < 16; m <<= 1){
    sq0 += __shfl_xor(sq0, m);
    sq1 += __shfl_xor(sq1, m);
    sq2 += __shfl_xor(sq2, m);
    sq3 += __shfl_xor(sq3, m);
  }
  if (cj == 0){
    f4 o = {sq0, sq1, sq2, sq3};
    *(f4*)&pnorm[((size_t)(e*16 + b)*8 + cT)*HW + hw0] = o;
  }
}

__global__ __launch_bounds__(256)
void norm_reduce(const float* __restrict__ pnorm, float* __restrict__ snorm){
  const int eb = blockIdx.x;
  const int t  = threadIdx.x;
  #pragma unroll
  for (int r = 0; r < 4; ++r){
    const int hw = r*256 + t;
    float a = 0.f;
    #pragma unroll
    for (int ct = 0; ct < 8; ++ct)
      a += pnorm[((size_t)eb*8 + ct)*HW + hw];
    snorm[(size_t)eb*HW + hw] = sqrtf(a);
  }
}

// ---------------------------------------------------------------------------
// Pass 2 (v5): v4's proven 256x256 / 8-wave / 3-buf / 1-barrier GEMM loop
// (0 bank conflicts) + CHEAP epilogue: reciprocal norms (no divides) and
// LDS two-phase top3 reduction (DS ops/wave 384 -> ~112).
// ---------------------------------------------------------------------------
__global__ __launch_bounds__(512, 2)
void fused_gemm_top3_v5(const unsigned short* __restrict__ tS,
                        const unsigned short* __restrict__ tR,
                        const float* __restrict__ snorm,
                        const int*   __restrict__ anchor,
                        const int*   __restrict__ posidx,
                        float* __restrict__ wtop,   // [NTOT][NCHUNK][3]
                        float* __restrict__ wpos)   // [NTOT]
{
  __shared__ unsigned short stage[49152];   // 96KB: A 3x16KB, B 3x16KB
  __shared__ int   p_lds[256], q_lds[256];
  __shared__ float nAs[256], nBs[256];      // RECIPROCAL norms

  const int t = threadIdx.x;
  const uint32_t bid = blockIdx.x;
  const uint32_t L = (bid & 7u)*32u + (bid >> 3);   // XCD swizzle (256%8==0)
  const int b  = L >> 4;
  const int ni = (L >> 2) & 3;
  const int mi = L & 3;

  const unsigned short* SbT = tS + (size_t)b*HW*CDIM;
  const unsigned short* RbT = tR + (size_t)b*HW*CDIM;

  if (t < 256){
    const int n_g = ni*256 + t;
    const int* ap = anchor + (size_t)(b*NA + n_g)*3;
    const int* pp = posidx + (size_t)(b*NA + n_g)*3;
    const int pv = ap[2]*FWID + ap[1];
    p_lds[t] = pv;
    q_lds[t] = pp[2]*FWID + pp[1];
    nAs[t] = 1.0f / snorm[(size_t)b*HW + pv];
  } else {
    nBs[t-256] = 1.0f / snorm[(size_t)(BATCH + b)*HW + mi*256 + (t-256)];
  }
  __syncthreads();

  const int l  = t & 63;
  const int w  = t >> 6;
  const int wr = w >> 2, wc = w & 3;

  const int gkc = (l&3) ^ ((l>>3)&3);
  const int r0  = w*32 + (l>>2);
  const int r1  = r0 + 16;
  const unsigned short* gA0 = SbT + (size_t)p_lds[r0]*CDIM + gkc*8;
  const unsigned short* gA1 = SbT + (size_t)p_lds[r1]*CDIM + gkc*8;
  const unsigned short* gB0 = RbT + (size_t)(mi*256 + r0)*CDIM + gkc*8;
  const unsigned short* gB1 = RbT + (size_t)(mi*256 + r1)*CDIM + gkc*8;
  unsigned short* lA = &stage[w*1024];
  unsigned short* lB = &stage[24576 + w*1024];

  const int fbase = (l&15)*32 + (((l>>4) ^ ((l>>1)&3))*8);
  const int abase = wr*4096 + fbase;
  const int bbase = 24576 + wc*2048 + fbase;

  f32x4 acc[8][4];
  #pragma unroll
  for (int i=0;i<8;i++){
    #pragma unroll
    for (int j=0;j<4;j++){ f32x4 z = {0.f,0.f,0.f,0.f}; acc[i][j] = z; }
  }

  auto stage_fn = [&](int bo, int kt){
    const int ko = kt*32;
    gload16(gA0 + ko, lA + bo);
    gload16(gA1 + ko, lA + bo + 512);
    gload16(gB0 + ko, lB + bo);
    gload16(gB1 + ko, lB + bo + 512);
  };

  auto compute = [&](int bo){
    FragU8 Bf[4], Af[8];
    #pragma unroll
    for (int fb=0; fb<4; ++fb) Bf[fb].u = *(const us8*)&stage[bbase + bo + fb*512];
    #pragma unroll
    for (int fa=0; fa<8; ++fa) Af[fa].u = *(const us8*)&stage[abase + bo + fa*512];
    #pragma unroll
    for (int fa=0; fa<8; ++fa){
      #pragma unroll
      for (int fb=0; fb<4; ++fb)
        acc[fa][fb] = MFMA(Af[fa].v, Bf[fb].v, acc[fa][fb], 0,0,0);
    }
  };

  // ---- main K loop (unchanged, proven): 32 tiles, depth-2, 1 barrier/tile ----
  stage_fn(0, 0);
  stage_fn(8192, 1);
  int oc = 0, on = 8192, on2 = 16384;
  for (int kt = 0; kt < 32; ++kt){
    if (kt < 31) asm volatile("s_waitcnt vmcnt(4)" ::: "memory");
    else         asm volatile("s_waitcnt vmcnt(0)" ::: "memory");
    asm volatile("s_waitcnt lgkmcnt(0)" ::: "memory");
    __builtin_amdgcn_s_barrier();
    if (kt < 30) stage_fn(on2, kt+2);
    compute(oc);
    const int tmp = oc; oc = on; on = on2; on2 = tmp;
  }

  // ---- epilogue v5: no divides, LDS two-phase top3 ----
  __syncthreads();   // all waves done reading stage -> safe to reuse as scratch

  // per-wave scratch: 16 rows x 17 f4 (pad for banks) = 4608 B
  float* tls = (float*)&stage[0] + (size_t)w*1152;

  float rinv[4];
  #pragma unroll
  for (int fb=0; fb<4; ++fb) rinv[fb] = nBs[wc*64 + fb*16 + (l&15)];

  #pragma unroll
  for (int fa=0; fa<8; ++fa){
    // phase 1: per-lane top3 of its 4 cols + positive capture; triple -> LDS
    #pragma unroll
    for (int r=0; r<4; ++r){
      const int rg    = (l>>4)*4 + r;            // row-in-group 0..15
      const int row_l = wr*128 + fa*16 + rg;
      const float ain = nAs[row_l];
      const float v0 = acc[fa][0][r] * ain * rinv[0];
      const float v1 = acc[fa][1][r] * ain * rinv[1];
      const float v2 = acc[fa][2][r] * ain * rinv[2];
      const float v3 = acc[fa][3][r] * ain * rinv[3];

      const int n_g = ni*256 + row_l;
      const int q   = q_lds[row_l];
      const int ql  = q - (mi*256 + wc*64);
      if (ql >= 0 && ql < 64 && (ql & 15) == (l & 15)){
        const int sel = ql >> 4;
        const float pv = sel==0 ? v0 : sel==1 ? v1 : sel==2 ? v2 : v3;
        wpos[b*NA + n_g] = pv;
      }

      float x=1e30f, y=1e30f, z=1e30f;
      ins3(x,y,z,v0); ins3(x,y,z,v1); ins3(x,y,z,v2); ins3(x,y,z,v3);
      f4 tr = {x, y, z, 0.f};
      *(f4*)(tls + (rg*17 + (l&15))*4) = tr;
    }
    asm volatile("s_waitcnt lgkmcnt(0)" ::: "memory");
    __builtin_amdgcn_sched_barrier(0);

    // phase 2: 4 lanes/row merge 4 triples each, then 2-step shfl merge
    {
      const int rr = l >> 2;
      const float* rbp = tls + (rr*17 + (l&3)*4)*4;
      const f4 t0 = *(const f4*)(rbp);
      const f4 t1 = *(const f4*)(rbp + 4);
      const f4 t2 = *(const f4*)(rbp + 8);
      const f4 t3 = *(const f4*)(rbp + 12);
      float x = t0[0], y = t0[1], z = t0[2];
      ins3(x,y,z,t1[0]); ins3(x,y,z,t1[1]); ins3(x,y,z,t1[2]);
      ins3(x,y,z,t2[0]); ins3(x,y,z,t2[1]); ins3(x,y,z,t2[2]);
      ins3(x,y,z,t3[0]); ins3(x,y,z,t3[1]); ins3(x,y,z,t3[2]);
      #pragma unroll
      for (int m=1; m<4; m<<=1){
        const float ox = __shfl_xor(x, m);
        const float oy = __shfl_xor(y, m);
        const float oz = __shfl_xor(z, m);
        ins3(x,y,z,ox); ins3(x,y,z,oy); ins3(x,y,z,oz);
      }
      if ((l & 3) == 0){
        const int n_g = ni*256 + wr*128 + fa*16 + rr;
        float* dst = wtop + ((size_t)(b*NA + n_g)*NCHUNK + (mi*4 + wc))*3;
        dst[0]=x; dst[1]=y; dst[2]=z;
      }
    }
    asm volatile("s_waitcnt lgkmcnt(0)" ::: "memory");
    __builtin_amdgcn_sched_barrier(0);
  }
}

// ---------------------------------------------------------------------------
// v1 (verified) fused kernel — fallback when workspace is too small.
// ---------------------------------------------------------------------------
__global__ __launch_bounds__(256)
void fused_gemm_top3_v1(const float* __restrict__ sketch,
                        const float* __restrict__ refk,
                        const int*   __restrict__ anchor,
                        const int*   __restrict__ posidx,
                        float* __restrict__ wtop,
                        float* __restrict__ wpos)
{
  __shared__ union {
    unsigned short stage[16384];
    struct { float nA[16][128]; float nB[16][128]; } nrm;
  } sh;
  __shared__ int   p_lds[128];
  __shared__ float nA2[128], nB2[128];

  const int t = threadIdx.x;
  const uint32_t bid = blockIdx.x;
  const uint32_t L = (bid & 7u)*128u + (bid >> 3);
  const int b  = L >> 6;
  const int ni = (L >> 3) & 7;
  const int mi = L & 7;

  const float* Sb = sketch + (size_t)b*CDIM*HW;
  const float* Rb = refk   + (size_t)b*CDIM*HW;

  if (t < 128){
    const int n_g = ni*128 + t;
    const int* ap = anchor + (size_t)(b*NA + n_g)*3;
    p_lds[t] = ap[2]*FWID + ap[1];
  }
  __syncthreads();
  const int p0 = p_lds[0];
  int okf = 1;
  if (t < 128) okf = (p_lds[t] == p0 + t);
  const int contig = __syncthreads_and(okf);

  const int colg = (t & 15)*8;
  const int rowg = t >> 4;
  const int mbase = mi*128;

  const int l  = t & 63;
  const int w  = t >> 6;
  const int wr = w >> 1, wc = w & 1;
  const uint32_t sh_base = (uint32_t)(uintptr_t)&sh.stage[0];
  const uint32_t laneA = ((uint32_t)(l>>4))*2048u + (uint32_t)wr*512u + (uint32_t)(l&15)*8u;
  const uint32_t laneB = ((uint32_t)(l>>4))*2048u + (uint32_t)wc*512u + (uint32_t)(l&15)*8u;
  const int off0 = ((rowg>>2)*8 + (colg>>4))*64 + (rowg&3)*16 + (colg&15);

  f32x4 acc[4][4];
  #pragma unroll
  for (int i=0;i<4;i++){
    #pragma unroll
    for (int j=0;j<4;j++){ f32x4 z = {0.f,0.f,0.f,0.f}; acc[i][j] = z; }
  }

  float sqA[8] = {0,0,0,0,0,0,0,0};
  float sqB[8] = {0,0,0,0,0,0,0,0};
  f4 ra[4], rb[4];

  auto load_tile = [&](int kt){
    const int c0 = kt*32 + rowg;
    const float* SA = Sb + (size_t)c0*HW;
    const float* RB = Rb + (size_t)c0*HW + mbase + colg;
    if (contig){
      const float* pA = SA + p0 + colg;
      ra[0] = *(const f4*)(pA);
      ra[1] = *(const f4*)(pA + 4);
      ra[2] = *(const f4*)(pA + 16*HW);
      ra[3] = *(const f4*)(pA + 16*HW + 4);
    } else {
      float* raf = (float*)ra;
      #pragma unroll
      for (int i=0;i<8;i++){
        const int pc = p_lds[colg + i];
        raf[i]   = SA[pc];
        raf[8+i] = SA[16*HW + pc];
      }
    }
    rb[0] = *(const f4*)(RB);
    rb[1] = *(const f4*)(RB + 4);
    rb[2] = *(const f4*)(RB + 16*HW);
    rb[3] = *(const f4*)(RB + 16*HW + 4);
  };

  auto cvt_store = [&](int buf){
    const float* raf = (const float*)ra;
    const float* rbf = (const float*)rb;
    us8 pk;
    #pragma unroll
    for (int i=0;i<8;i++){
      __hip_bfloat16 h = __float2bfloat16(raf[i]);
      pk[i] = __builtin_bit_cast(unsigned short, h);
      const float g = __bfloat162float(h);
      sqA[i] = fmaf(g, g, sqA[i]);
    }
    *(us8*)&sh.stage[buf*4096 + off0] = pk;
    #pragma unroll
    for (int i=0;i<8;i++){
      __hip_bfloat16 h = __float2bfloat16(raf[8+i]);
      pk[i] = __builtin_bit_cast(unsigned short, h);
      const float g = __bfloat162float(h);
      sqA[i] = fmaf(g, g, sqA[i]);
    }
    *(us8*)&sh.stage[buf*4096 + off0 + 2048] = pk;
    #pragma unroll
    for (int i=0;i<8;i++){
      __hip_bfloat16 h = __float2bfloat16(rbf[i]);
      pk[i] = __builtin_bit_cast(unsigned short, h);
      const float g = __bfloat162float(h);
      sqB[i] = fmaf(g, g, sqB[i]);
    }
    *(us8*)&sh.stage[8192 + buf*4096 + off0] = pk;
    #pragma unroll
    for (int i=0;i<8;i++){
      __hip_bfloat16 h = __float2bfloat16(rbf[8+i]);
      pk[i] = __builtin_bit_cast(unsigned short, h);
      const float g = __bfloat162float(h);
      sqB[i] = fmaf(g, g, sqB[i]);
    }
    *(us8*)&sh.stage[8192 + buf*4096 + off0 + 2048] = pk;
  };

  auto compute = [&](int buf){
    const uint32_t aaddr = sh_base + (uint32_t)buf*8192u + laneA;
    const uint32_t baddr = sh_base + 16384u + (uint32_t)buf*8192u + laneB;
    FragU A0,A1,A2,A3,B0,B1,B2,B3;
    A0.h[0]=tr_read<0>(aaddr);    A0.h[1]=tr_read<1024>(aaddr);
    A1.h[0]=tr_read<128>(aaddr);  A1.h[1]=tr_read<1152>(aaddr);
    A2.h[0]=tr_read<256>(aaddr);  A2.h[1]=tr_read<1280>(aaddr);
    A3.h[0]=tr_read<384>(aaddr);  A3.h[1]=tr_read<1408>(aaddr);
    B0.h[0]=tr_read<0>(baddr);    B0.h[1]=tr_read<1024>(baddr);
    B1.h[0]=tr_read<128>(baddr);  B1.h[1]=tr_read<1152>(baddr);
    B2.h[0]=tr_read<256>(baddr);  B2.h[1]=tr_read<1280>(baddr);
    B3.h[0]=tr_read<384>(baddr);  B3.h[1]=tr_read<1408>(baddr);
    asm volatile("s_waitcnt lgkmcnt(0)" ::: "memory");
    __builtin_amdgcn_sched_barrier(0);
    acc[0][0]=MFMA(A0.v,B0.v,acc[0][0],0,0,0);
    acc[0][1]=MFMA(A0.v,B1.v,acc[0][1],0,0,0);
    acc[0][2]=MFMA(A0.v,B2.v,acc[0][2],0,0,0);
    acc[0][3]=MFMA(A0.v,B3.v,acc[0][3],0,0,0);
    acc[1][0]=MFMA(A1.v,B0.v,acc[1][0],0,0,0);
    acc[1][1]=MFMA(A1.v,B1.v,acc[1][1],0,0,0);
    acc[1][2]=MFMA(A1.v,B2.v,acc[1][2],0,0,0);
    acc[1][3]=MFMA(A1.v,B3.v,acc[1][3],0,0,0);
    acc[2][0]=MFMA(A2.v,B0.v,acc[2][0],0,0,0);
    acc[2][1]=MFMA(A2.v,B1.v,acc[2][1],0,0,0);
    acc[2][2]=MFMA(A2.v,B2.v,acc[2][2],0,0,0);
    acc[2][3]=MFMA(A2.v,B3.v,acc[2][3],0,0,0);
    acc[3][0]=MFMA(A3.v,B0.v,acc[3][0],0,0,0);
    acc[3][1]=MFMA(A3.v,B1.v,acc[3][1],0,0,0);
    acc[3][2]=MFMA(A3.v,B2.v,acc[3][2],0,0,0);
    acc[3][3]=MFMA(A3.v,B3.v,acc[3][3],0,0,0);
  };

  load_tile(0);
  cvt_store(0);
  __syncthreads();
  int buf = 0;
  for (int kt = 0; kt < 32; ++kt){
    if (kt < 31) load_tile(kt+1);
    compute(buf);
    if (kt < 31) cvt_store(buf^1);
    __syncthreads();
    buf ^= 1;
  }

  #pragma unroll
  for (int i=0;i<8;i++) sh.nrm.nA[rowg][colg+i] = sqA[i];
  #pragma unroll
  for (int i=0;i<8;i++) sh.nrm.nB[rowg][colg+i] = sqB[i];
  __syncthreads();
  if (t < 128){
    float s = 0.f;
    #pragma unroll
    for (int r=0;r<16;r++) s += sh.nrm.nA[r][t];
    nA2[t] = s;
  } else {
    const int c2 = t - 128;
    float s = 0.f;
    #pragma unroll
    for (int r=0;r<16;r++) s += sh.nrm.nB[r][c2];
    nB2[c2] = s;
  }
  __syncthreads();

  float rncol[4];
  #pragma unroll
  for (int nf=0;nf<4;nf++) rncol[nf] = sqrtf(nB2[wc*64 + nf*16 + (l&15)]);

  #pragma unroll
  for (int mf=0; mf<4; ++mf){
    #pragma unroll
    for (int r=0; r<4; ++r){
      const int row_l = wr*64 + mf*16 + (l>>4)*4 + r;
      const int n_g   = ni*128 + row_l;
      const float an  = sqrtf(nA2[row_l]);
      const float v0 = acc[mf][0][r] / fmaxf(an*rncol[0], 1e-8f);
      const float v1 = acc[mf][1][r] / fmaxf(an*rncol[1], 1e-8f);
      const float v2 = acc[mf][2][r] / fmaxf(an*rncol[2], 1e-8f);
      const float v3 = acc[mf][3][r] / fmaxf(an*rncol[3], 1e-8f);

      const int* pp = posidx + (size_t)(b*NA + n_g)*3;
      const int q  = pp[2]*FWID + pp[1];
      const int ql = q - (mbase + wc*64);
      if (ql >= 0 && ql < 64 && (ql & 15) == (l & 15)){
        const int sel = ql >> 4;
        const float pv = sel==0 ? v0 : sel==1 ? v1 : sel==2 ? v2 : v3;
        wpos[b*NA + n_g] = pv;
      }

      float x=1e30f, y=1e30f, z=1e30f;
      ins3(x,y,z,v0); ins3(x,y,z,v1); ins3(x,y,z,v2); ins3(x,y,z,v3);
      #pragma unroll
      for (int m=1; m<16; m<<=1){
        const float ox = __shfl_xor(x, m);
        const float oy = __shfl_xor(y, m);
        const float oz = __shfl_xor(z, m);
        ins3(x,y,z,ox); ins3(x,y,z,oy); ins3(x,y,z,oz);
      }
      if ((l & 15) == 0){
        float* dst = wtop + ((size_t)(b*NA + n_g)*NCHUNK + (mi*2 + wc))*3;
        dst[0]=x; dst[1]=y; dst[2]=z;
      }
    }
  }
}

// ---------------------------------------------------------------------------
__global__ __launch_bounds__(256)
void merge_top3(const float* __restrict__ wtop, const float* __restrict__ wpos,
                float* __restrict__ partial){
  __shared__ float red[256];
  const int id = blockIdx.x*256 + threadIdx.x;
  const float* src = wtop + (size_t)id*(NCHUNK*3);
  float x=1e30f, y=1e30f, z=1e30f;
  #pragma unroll
  for (int i=0;i<NCHUNK*3;i++) ins3(x,y,z, src[i]);
  const float loss = fmaxf((x+y+z) - wpos[id] + MARGIN, 0.0f);
  red[threadIdx.x] = loss;
  __syncthreads();
  for (int s=128; s>0; s>>=1){
    if (threadIdx.x < s) red[threadIdx.x] += red[threadIdx.x+s];
    __syncthreads();
  }
  if (threadIdx.x == 0) partial[blockIdx.x] = red[0];
}

__global__ void final_sum(const float* __restrict__ partial, float* __restrict__ out){
  float v = partial[threadIdx.x];
  #pragma unroll
  for (int off=32; off>0; off>>=1) v += __shfl_down(v, off);
  if (threadIdx.x == 0) out[0] = v / (1e-6f + (float)NTOT);
}

// ---------------------------------------------------------------------------
extern "C" void kernel_launch(void* const* d_in, const int* in_sizes, int n_in,
                              void* d_out, int out_size, void* d_ws, size_t ws_size,
                              hipStream_t stream){
  const float* sketch = (const float*)d_in[0];
  const float* refk   = (const float*)d_in[1];
  const int*   anchor = (const int*)d_in[2];
  const int*   posidx = (const int*)d_in[3];
  float* out = (float*)d_out;

  float* wtop    = (float*)d_ws;                       // NTOT*NCHUNK*3 floats
  float* wpos    = wtop + (size_t)NTOT*NCHUNK*3;       // NTOT floats
  float* partial = wpos + NTOT;                        // 64 floats (+pad)
  unsigned short* tS = (unsigned short*)(partial + 256);
  unsigned short* tR = tS + (size_t)BATCH*HW*CDIM;
  float* pnorm = (float*)(tR + (size_t)BATCH*HW*CDIM); // 32*8*1024 floats
  float* snorm = pnorm + (size_t)32*8*1024;            // 32*1024 floats
  const size_t need = (size_t)((char*)(snorm + 32*1024) - (char*)d_ws);

  if (ws_size >= need){
    convert_transpose<<<dim3(4096), dim3(256), 0, stream>>>(sketch, refk, tS, tR, pnorm);
    norm_reduce<<<dim3(32), dim3(256), 0, stream>>>(pnorm, snorm);
    fused_gemm_top3_v5<<<dim3(256), dim3(512), 0, stream>>>(tS, tR, snorm, anchor, posidx, wtop, wpos);
  } else {
    fused_gemm_top3_v1<<<dim3(1024), dim3(256), 0, stream>>>(sketch, refk, anchor, posidx, wtop, wpos);
  }
  merge_top3<<<dim3(64), dim3(256), 0, stream>>>(wtop, wpos, partial);
  final_sum<<<dim3(1), dim3(64), 0, stream>>>(partial, out);
}